// Round 5
// baseline (111052.771 us; speedup 1.0000x reference)
//
#include <hip/hip_runtime.h>
#include <stdint.h>

#define NIN  64
#define NRES 2048
#define NOUT 64
#define BB   32
#define TT   1024

// y[b][t][o] = b_out[o] (seed for atomic accumulation); zero h0
__global__ __launch_bounds__(256) void esn_init(const float* __restrict__ b_out,
                                                float* __restrict__ y,
                                                float* __restrict__ h0) {
  int idx = blockIdx.x * 256 + threadIdx.x;   // grid 8192*256 = 2,097,152
  y[idx] = b_out[idx & 63];
  if (idx < NRES * BB) h0[idx] = 0.0f;
}

// One recurrence step with fused partial readout:
//   h_out[r][b] = tanh(b_res[r] + W_in[r,:]@x[b,t,:] + W_res[r,:]@h_in[:,b])
//   y[b][t][o] += sum_{r in block} h[r][b] * W_out[o][r]   (atomic, f32)
__global__ __launch_bounds__(256) void esn_step(
    const float* __restrict__ x,      // [B][T][64]   f32
    const float* __restrict__ W_in,   // [2048][64]   f32
    const float* __restrict__ W_res,  // [2048][2048] f32
    const float* __restrict__ b_res,  // [2048]       f32
    const float* __restrict__ W_out,  // [64][2048]   f32
    const float* __restrict__ h_in,   // [2048][32]   f32 (k-major, b minor)
    float*       __restrict__ h_out,  // [2048][32]   f32
    float*       __restrict__ y,      // [B][T][64]   f32 (accumulated)
    int t)
{
  __shared__ float xs[BB][NIN + 1];   // x slice, padded: bank = (b+d)%32, conflict-free
  __shared__ float hs[8][BB + 1];     // this block's 8 h-rows
  __shared__ float wos[NOUT][9];      // W_out[o][r0..r0+7], padded

  int tid = threadIdx.x;
  int r0  = blockIdx.x << 3;          // 8 rows per block, grid = 256

  { // stage x[., t, .] : 256 threads * 8 f32 = 2048 = BB*NIN
    int i = tid * 8, b = i >> 6, d = i & 63;
    const float* src = x + (size_t)b * (TT * NIN) + (size_t)t * NIN + d;
    float4 v0 = *reinterpret_cast<const float4*>(src);
    float4 v1 = *reinterpret_cast<const float4*>(src + 4);
    xs[b][d + 0] = v0.x; xs[b][d + 1] = v0.y; xs[b][d + 2] = v0.z; xs[b][d + 3] = v0.w;
    xs[b][d + 4] = v1.x; xs[b][d + 5] = v1.y; xs[b][d + 6] = v1.z; xs[b][d + 7] = v1.w;
  }
  { // stage W_out column slice: 64 o * 8 r = 512 f32, 2 per thread (float2, 8B aligned)
    int o = tid >> 2, jj = (tid & 3) * 2;
    float2 w2 = *reinterpret_cast<const float2*>(W_out + (size_t)o * NRES + r0 + jj);
    wos[o][jj]     = w2.x;
    wos[o][jj + 1] = w2.y;
  }
  __syncthreads();

  int b  = tid & 31;                  // lanes over batch -> coalesced h loads
  int rr = tid >> 5;                  // 0..7
  int r  = r0 + rr;

  float acc = b_res[r];

  const float* wi = W_in + (size_t)r * NIN;
#pragma unroll
  for (int d = 0; d < NIN; d += 8) {
    float4 w0 = *reinterpret_cast<const float4*>(wi + d);
    float4 w1 = *reinterpret_cast<const float4*>(wi + d + 4);
    acc += w0.x * xs[b][d + 0] + w0.y * xs[b][d + 1] +
           w0.z * xs[b][d + 2] + w0.w * xs[b][d + 3] +
           w1.x * xs[b][d + 4] + w1.y * xs[b][d + 5] +
           w1.z * xs[b][d + 6] + w1.w * xs[b][d + 7];
  }

  const float* wr  = W_res + (size_t)r * NRES;
  const float* hbp = h_in + b;
  for (int k = 0; k < NRES; k += 8) {
    float4 w0 = *reinterpret_cast<const float4*>(wr + k);
    float4 w1 = *reinterpret_cast<const float4*>(wr + k + 4);
    acc += w0.x * hbp[(size_t)(k + 0) * BB] + w0.y * hbp[(size_t)(k + 1) * BB] +
           w0.z * hbp[(size_t)(k + 2) * BB] + w0.w * hbp[(size_t)(k + 3) * BB] +
           w1.x * hbp[(size_t)(k + 4) * BB] + w1.y * hbp[(size_t)(k + 5) * BB] +
           w1.z * hbp[(size_t)(k + 6) * BB] + w1.w * hbp[(size_t)(k + 7) * BB];
  }

  float h = tanhf(acc);
  h_out[r * BB + b] = h;
  hs[rr][b] = h;
  __syncthreads();

  float h8[8];
#pragma unroll
  for (int j = 0; j < 8; ++j) h8[j] = hs[j][b];

  float* yrow = y + (size_t)b * (TT * NOUT) + (size_t)t * NOUT;
#pragma unroll
  for (int oo = 0; oo < 8; ++oo) {
    int o = oo * 8 + rr;
    float p = 0.f;
#pragma unroll
    for (int j = 0; j < 8; ++j) p += h8[j] * wos[o][j];
    atomicAdd(yrow + o, p);
  }
}

extern "C" void kernel_launch(void* const* d_in, const int* in_sizes, int n_in,
                              void* d_out, int out_size, void* d_ws, size_t ws_size,
                              hipStream_t stream) {
  // Resolve inputs by flat element count (dtype-independent, robust to ordering).
  const float* p_x = 0; const float* p_Win = 0; const float* p_Wres = 0;
  const float* p_bres = 0; const float* p_Wout = 0; const float* p_bout = 0;
  for (int i = 0; i < n_in; ++i) {
    const float* p = (const float*)d_in[i];
    switch (in_sizes[i]) {
      case 2097152: p_x = p; break;
      case 4194304: p_Wres = p; break;
      case 2048:    p_bres = p; break;
      case 64:      p_bout = p; break;
      case 131072:  if (!p_Win) p_Win = p; else p_Wout = p; break;  // dict order: W_in before W_out
      default: break;
    }
  }
  if (!p_x || !p_Win || !p_Wres || !p_bres || !p_Wout || !p_bout) {
    p_x    = (const float*)d_in[0];
    p_Win  = (const float*)d_in[1];
    p_Wres = (const float*)d_in[2];
    p_bres = (const float*)d_in[3];
    p_Wout = (const float*)d_in[4];
    p_bout = (const float*)d_in[5];
  }

  float* y = (float*)d_out;                        // f32 output [B][T][64]
  float* h0 = (float*)d_ws;                        // 262,144 B
  float* h1 = (float*)((char*)d_ws + 262144);      // 262,144 B

  esn_init<<<dim3(8192), dim3(256), 0, stream>>>(p_bout, y, h0);

  float* ha = h0;
  float* hb = h1;
  for (int t = 0; t < TT; ++t) {
    esn_step<<<dim3(256), dim3(256), 0, stream>>>(p_x, p_Win, p_Wres, p_bres, p_Wout,
                                                  ha, hb, y, t);
    float* tmp = ha; ha = hb; hb = tmp;
  }
}

// Round 7
// 17130.104 us; speedup vs baseline: 6.4829x; 6.4829x over previous
//
#include <hip/hip_runtime.h>
#include <stdint.h>

#define NRES 2048
#define NIN  64
#define NOUT 64
#define BB   32
#define TT   1024

typedef __attribute__((ext_vector_type(8))) short bf16x8;
typedef __attribute__((ext_vector_type(4))) float f32x4;

__device__ __forceinline__ float bf2f(uint16_t u) {
  union { uint32_t i; float f; } v; v.i = ((uint32_t)u) << 16; return v.f;
}
__device__ __forceinline__ uint16_t f2bf_rne(float f) {
  union { float f; uint32_t i; } v; v.f = f;
  uint32_t lsb = (v.i >> 16) & 1u;
  v.i += 0x7fffu + lsb;
  return (uint16_t)(v.i >> 16);
}
__device__ __forceinline__ short hi16(float f) {
  return (short)(__float_as_uint(f) >> 16);   // exact: inputs are bf16-representable
}
__device__ __forceinline__ bf16x8 pack8(float4 a, float4 b) {
  bf16x8 r;
  r[0] = hi16(a.x); r[1] = hi16(a.y); r[2] = hi16(a.z); r[3] = hi16(a.w);
  r[4] = hi16(b.x); r[5] = hi16(b.y); r[6] = hi16(b.z); r[7] = hi16(b.w);
  return r;
}

// y[b][t][o] = b_out[o] (seed for atomic accumulation); zero the hA hi/lo pair
__global__ __launch_bounds__(256) void esn_init(const float* __restrict__ b_out,
                                                float* __restrict__ y,
                                                uint32_t* __restrict__ hz) {
  int idx = blockIdx.x * 256 + threadIdx.x;   // grid 8192 -> 2,097,152
  y[idx] = b_out[idx & 63];
  if (idx < 65536) hz[idx] = 0u;              // 262,144 B = h_hi + h_lo (contiguous)
}

// One step. Block = 16 reservoir rows x 16 batches. 8 waves K-split the 2048 dot.
// h kept as two-term bf16 (hi+lo) => ~f32 recurrence fidelity through MFMA.
__global__ __launch_bounds__(512) void esn_step(
    const float* __restrict__ x,        // [32][1024][64] f32 (bf16-exact values)
    const float* __restrict__ W_in,     // [2048][64]
    const float* __restrict__ W_res,    // [2048][2048]
    const float* __restrict__ b_res,    // [2048]
    const float* __restrict__ W_out,    // [64][2048]
    const uint16_t* __restrict__ h_hi,  // [32][2048] bf16
    const uint16_t* __restrict__ h_lo,  // [32][2048] bf16
    uint16_t* __restrict__ ho_hi,       // [32][2048] bf16
    uint16_t* __restrict__ ho_lo,       // [32][2048] bf16
    float* __restrict__ y,              // [32][1024][64] f32 (atomic accumulate)
    int t)
{
  __shared__ float wos[NOUT][17];       // W_out[o][r0..r0+15]
  __shared__ float red[8][16][17];      // [wave][rowM][colB]
  __shared__ float hs[16][17];          // h_new f32 for readout

  int tid   = threadIdx.x;
  int l     = tid & 63;
  int w     = tid >> 6;                 // wave 0..7 -> K slice of 256
  int btile = blockIdx.x & 1;           // batch half
  int r0    = (blockIdx.x >> 1) << 4;   // 128 row tiles
  int m16   = l & 15;
  int kg    = l >> 4;                   // 0..3

  if (tid < 256) {                      // stage W_out slice (read after barrier)
    int o = tid >> 2, jj = (tid & 3) * 4;
    float4 wv = *reinterpret_cast<const float4*>(W_out + (size_t)o * NRES + r0 + jj);
    wos[o][jj + 0] = wv.x; wos[o][jj + 1] = wv.y;
    wos[o][jj + 2] = wv.z; wos[o][jj + 3] = wv.w;
  }

  int b = btile * 16 + m16;             // B-frag column n = batch
  f32x4 acc = {0.f, 0.f, 0.f, 0.f};

  const float*    ap = W_res + (size_t)(r0 + m16) * NRES + w * 256 + kg * 8;
  const uint16_t* bh = h_hi + (size_t)b * NRES + w * 256 + kg * 8;
  const uint16_t* bl = h_lo + (size_t)b * NRES + w * 256 + kg * 8;
#pragma unroll
  for (int c = 0; c < 8; ++c) {         // 8 chunks of K=32
    float4 a0 = *reinterpret_cast<const float4*>(ap);
    float4 a1 = *reinterpret_cast<const float4*>(ap + 4);
    bf16x8 af  = pack8(a0, a1);
    bf16x8 bh8 = *reinterpret_cast<const bf16x8*>(bh);
    bf16x8 bl8 = *reinterpret_cast<const bf16x8*>(bl);
    acc = __builtin_amdgcn_mfma_f32_16x16x32_bf16(af, bh8, acc, 0, 0, 0);
    acc = __builtin_amdgcn_mfma_f32_16x16x32_bf16(af, bl8, acc, 0, 0, 0);
    ap += 32; bh += 32; bl += 32;
  }

  if (w == 0) {                         // fold U = W_in @ x_t (K=64)
    const float* aip = W_in + (size_t)(r0 + m16) * NIN + kg * 8;
    const float* xp  = x + (size_t)b * (TT * NIN) + (size_t)t * NIN + kg * 8;
#pragma unroll
    for (int c = 0; c < 2; ++c) {
      float4 a0 = *reinterpret_cast<const float4*>(aip);
      float4 a1 = *reinterpret_cast<const float4*>(aip + 4);
      float4 x0 = *reinterpret_cast<const float4*>(xp);
      float4 x1 = *reinterpret_cast<const float4*>(xp + 4);
      acc = __builtin_amdgcn_mfma_f32_16x16x32_bf16(pack8(a0, a1), pack8(x0, x1), acc, 0, 0, 0);
      aip += 32; xp += 32;
    }
  }

#pragma unroll
  for (int j = 0; j < 4; ++j) red[w][kg * 4 + j][m16] = acc[j];  // D: row=(l>>4)*4+j, col=l&15
  __syncthreads();

  if (tid < 256) {                      // reduce 8 waves, tanh, split hi/lo, store
    int rowM = tid & 15, colB = tid >> 4;
    float s = b_res[r0 + rowM];
#pragma unroll
    for (int ww = 0; ww < 8; ++ww) s += red[ww][rowM][colB];
    float h = tanhf(s);
    uint16_t hh = f2bf_rne(h);
    float rem = h - bf2f(hh);
    uint16_t hl = f2bf_rne(rem);
    int bg = btile * 16 + colB;
    ho_hi[(size_t)bg * NRES + r0 + rowM] = hh;
    ho_lo[(size_t)bg * NRES + r0 + rowM] = hl;
    hs[rowM][colB] = h;
  }
  __syncthreads();

  // fused readout: y[b][t][o] += W_out[o][r0..r0+15] . h_new[.., b]
#pragma unroll
  for (int q = 0; q < 2; ++q) {
    int p = tid * 2 + q;                // 1024 (o, colB) pairs
    int o = p >> 4, colB = p & 15;
    float d = 0.f;
#pragma unroll
    for (int rm = 0; rm < 16; ++rm) d += wos[o][rm] * hs[rm][colB];
    atomicAdd(y + (size_t)(btile * 16 + colB) * (TT * NOUT) + (size_t)t * NOUT + o, d);
  }
}

// ---------------- legacy dense-VALU fallback (tiny ws) ----------------------
__global__ __launch_bounds__(256) void legacy_init(const float* __restrict__ b_out,
                                                   float* __restrict__ y,
                                                   float* __restrict__ h0) {
  int idx = blockIdx.x * 256 + threadIdx.x;
  y[idx] = b_out[idx & 63];
  if (idx < NRES * BB) h0[idx] = 0.0f;
}

__global__ __launch_bounds__(256) void legacy_step(
    const float* __restrict__ x, const float* __restrict__ W_in,
    const float* __restrict__ W_res, const float* __restrict__ b_res,
    const float* __restrict__ W_out, const float* __restrict__ h_in,
    float* __restrict__ h_out, float* __restrict__ y, int t)
{
  __shared__ float xs[BB][NIN + 1];
  __shared__ float hsL[8][BB + 1];
  __shared__ float wosL[NOUT][9];
  int tid = threadIdx.x;
  int r0  = blockIdx.x << 3;
  {
    int i = tid * 8, b = i >> 6, d = i & 63;
    const float* src = x + (size_t)b * (TT * NIN) + (size_t)t * NIN + d;
    float4 v0 = *reinterpret_cast<const float4*>(src);
    float4 v1 = *reinterpret_cast<const float4*>(src + 4);
    xs[b][d + 0] = v0.x; xs[b][d + 1] = v0.y; xs[b][d + 2] = v0.z; xs[b][d + 3] = v0.w;
    xs[b][d + 4] = v1.x; xs[b][d + 5] = v1.y; xs[b][d + 6] = v1.z; xs[b][d + 7] = v1.w;
  }
  {
    int o = tid >> 2, jj = (tid & 3) * 2;
    float2 w2 = *reinterpret_cast<const float2*>(W_out + (size_t)o * NRES + r0 + jj);
    wosL[o][jj] = w2.x; wosL[o][jj + 1] = w2.y;
  }
  __syncthreads();
  int b = tid & 31, rr = tid >> 5, r = r0 + rr;
  float acc = b_res[r];
  const float* wi = W_in + (size_t)r * NIN;
#pragma unroll
  for (int d = 0; d < NIN; d += 8) {
    float4 w0 = *reinterpret_cast<const float4*>(wi + d);
    float4 w1 = *reinterpret_cast<const float4*>(wi + d + 4);
    acc += w0.x * xs[b][d + 0] + w0.y * xs[b][d + 1] + w0.z * xs[b][d + 2] + w0.w * xs[b][d + 3] +
           w1.x * xs[b][d + 4] + w1.y * xs[b][d + 5] + w1.z * xs[b][d + 6] + w1.w * xs[b][d + 7];
  }
  const float* wr = W_res + (size_t)r * NRES;
  const float* hbp = h_in + b;
  for (int k = 0; k < NRES; k += 8) {
    float4 w0 = *reinterpret_cast<const float4*>(wr + k);
    float4 w1 = *reinterpret_cast<const float4*>(wr + k + 4);
    acc += w0.x * hbp[(size_t)(k + 0) * BB] + w0.y * hbp[(size_t)(k + 1) * BB] +
           w0.z * hbp[(size_t)(k + 2) * BB] + w0.w * hbp[(size_t)(k + 3) * BB] +
           w1.x * hbp[(size_t)(k + 4) * BB] + w1.y * hbp[(size_t)(k + 5) * BB] +
           w1.z * hbp[(size_t)(k + 6) * BB] + w1.w * hbp[(size_t)(k + 7) * BB];
  }
  float h = tanhf(acc);
  h_out[r * BB + b] = h;
  hsL[rr][b] = h;
  __syncthreads();
  float h8[8];
#pragma unroll
  for (int j = 0; j < 8; ++j) h8[j] = hsL[j][b];
  float* yrow = y + (size_t)b * (TT * NOUT) + (size_t)t * NOUT;
#pragma unroll
  for (int oo = 0; oo < 8; ++oo) {
    int o = oo * 8 + rr;
    float p = 0.f;
#pragma unroll
    for (int j = 0; j < 8; ++j) p += h8[j] * wosL[o][j];
    atomicAdd(yrow + o, p);
  }
}

// ---------------------------------------------------------------------------
extern "C" void kernel_launch(void* const* d_in, const int* in_sizes, int n_in,
                              void* d_out, int out_size, void* d_ws, size_t ws_size,
                              hipStream_t stream) {
  const float* p_x = 0; const float* p_Win = 0; const float* p_Wres = 0;
  const float* p_bres = 0; const float* p_Wout = 0; const float* p_bout = 0;
  for (int i = 0; i < n_in; ++i) {
    const float* p = (const float*)d_in[i];
    switch (in_sizes[i]) {
      case 2097152: p_x = p; break;
      case 4194304: p_Wres = p; break;
      case 2048:    p_bres = p; break;
      case 64:      p_bout = p; break;
      case 131072:  if (!p_Win) p_Win = p; else p_Wout = p; break;  // dict order: W_in first
      default: break;
    }
  }
  if (!p_x || !p_Win || !p_Wres || !p_bres || !p_Wout || !p_bout) {
    p_x    = (const float*)d_in[0];
    p_Win  = (const float*)d_in[1];
    p_Wres = (const float*)d_in[2];
    p_bres = (const float*)d_in[3];
    p_Wout = (const float*)d_in[4];
    p_bout = (const float*)d_in[5];
  }

  float* y = (float*)d_out;

  // ws: [hA_hi 128K][hA_lo 128K][hB_hi 128K][hB_lo 128K] = 512 KiB, ping-pong only
  if (ws_size >= 524288) {
    uint16_t* hA_hi = (uint16_t*)d_ws;
    uint16_t* hA_lo = (uint16_t*)((char*)d_ws + 131072);
    uint16_t* hB_hi = (uint16_t*)((char*)d_ws + 262144);
    uint16_t* hB_lo = (uint16_t*)((char*)d_ws + 393216);

    esn_init<<<dim3(8192), dim3(256), 0, stream>>>(p_bout, y, (uint32_t*)d_ws);

    uint16_t *ihi = hA_hi, *ilo = hA_lo, *ohi = hB_hi, *olo = hB_lo;
    for (int t = 0; t < TT; ++t) {
      esn_step<<<dim3(256), dim3(512), 0, stream>>>(p_x, p_Win, p_Wres, p_bres, p_Wout,
                                                    ihi, ilo, ohi, olo, y, t);
      uint16_t* s;
      s = ihi; ihi = ohi; ohi = s;
      s = ilo; ilo = olo; olo = s;
    }
  } else {
    float* h0 = (float*)d_ws;
    float* h1 = (float*)((char*)d_ws + 262144);
    legacy_init<<<dim3(8192), dim3(256), 0, stream>>>(p_bout, y, h0);
    float* ha = h0; float* hb = h1;
    for (int t = 0; t < TT; ++t) {
      legacy_step<<<dim3(256), dim3(256), 0, stream>>>(p_x, p_Win, p_Wres, p_bres, p_Wout,
                                                       ha, hb, y, t);
      float* tmp = ha; ha = hb; hb = tmp;
    }
  }
}